// Round 13
// baseline (547.122 us; speedup 1.0000x reference)
//
#include <hip/hip_runtime.h>
#include <hip/hip_bf16.h>
#include <stdint.h>

#define NL   8192
#define NHI  1024
#define DIMV 2048

typedef __attribute__((ext_vector_type(8))) short short8;
typedef __attribute__((ext_vector_type(4))) float f32x4;

__device__ __forceinline__ unsigned short f2bf(float x){
  unsigned u = __float_as_uint(x);
  u += 0x7FFFu + ((u >> 16) & 1u);
  return (unsigned short)(u >> 16);
}
__device__ __forceinline__ float bf2f(unsigned short b){
  return __uint_as_float(((unsigned)b) << 16);
}
__device__ __forceinline__ unsigned pack2bf(float a, float b){
  return (unsigned)f2bf(a) | ((unsigned)f2bf(b) << 16);
}

__device__ __forceinline__ void gload16(const void* g, void* l){
  __builtin_amdgcn_global_load_lds(
      (const __attribute__((address_space(1))) unsigned int*)g,
      (__attribute__((address_space(3))) unsigned int*)l, 16, 0, 0);
}

// ---- fused prep: rownorm(low)+rownorm(high) [0,9216) | castT(Wq) [9216,10240)
//      | plain cast(Wk) [10240,12288) ----
__global__ __launch_bounds__(256)
void prep_kernel(const float* __restrict__ low_w, const float* __restrict__ high_w,
                 const float* __restrict__ Wq, const float* __restrict__ Wk,
                 float* __restrict__ out_lowc, unsigned short* __restrict__ lowN,
                 unsigned short* __restrict__ highN,
                 unsigned short* __restrict__ WqT, unsigned short* __restrict__ WkB){
  __shared__ __align__(16) char smem[8448];
  int id = blockIdx.x;
  if(id < 9216){
    const float* W; float* oF; unsigned short* oB; int row;
    if(id < 8192){ W = low_w; oF = out_lowc; oB = lowN; row = id; }
    else         { W = high_w; oF = nullptr; oB = highN; row = id - 8192; }
    const float* r = W + (size_t)row * DIMV;
    int base = threadIdx.x * 8;
    float4 x0 = *(const float4*)(r + base);
    float4 x1 = *(const float4*)(r + base + 4);
    float ss = x0.x*x0.x + x0.y*x0.y + x0.z*x0.z + x0.w*x0.w
             + x1.x*x1.x + x1.y*x1.y + x1.z*x1.z + x1.w*x1.w;
    #pragma unroll
    for(int s = 1; s < 64; s <<= 1) ss += __shfl_xor(ss, s, 64);
    float* red = (float*)smem;
    if((threadIdx.x & 63) == 0) red[threadIdx.x >> 6] = ss;
    __syncthreads();
    float tot = red[0] + red[1] + red[2] + red[3];
    float inv = 1.0f / sqrtf(tot);
    float y0=x0.x*inv, y1=x0.y*inv, y2=x0.z*inv, y3=x0.w*inv;
    float y4=x1.x*inv, y5=x1.y*inv, y6=x1.z*inv, y7=x1.w*inv;
    if(oF){
      float* o = oF + (size_t)row * DIMV + base;
      *(float4*)o       = make_float4(y0,y1,y2,y3);
      *(float4*)(o + 4) = make_float4(y4,y5,y6,y7);
    }
    uint4 u;
    u.x = pack2bf(y0,y1); u.y = pack2bf(y2,y3);
    u.z = pack2bf(y4,y5); u.w = pack2bf(y6,y7);
    *(uint4*)(oB + (size_t)row * DIMV + base) = u;
  } else if(id < 10240){
    id -= 9216;                                // Wq cast+transpose tiles
    unsigned short (*tile)[65] = (unsigned short(*)[65])smem;
    int tx = id & 31, ty = id >> 5;
    int c0 = tx * 64, r0 = ty * 64;
    int t = threadIdx.x;
    int ci = t & 63, r4 = t >> 6;
    #pragma unroll
    for(int k = 0; k < 16; k++){
      int r = k * 4 + r4;
      tile[r][ci] = f2bf(Wq[(size_t)(r0 + r) * 2048 + c0 + ci]);
    }
    __syncthreads();
    #pragma unroll
    for(int k = 0; k < 16; k++){
      int cc = k * 4 + r4;
      WqT[(size_t)(c0 + cc) * 2048 + r0 + ci] = tile[ci][cc];
    }
  } else {
    id -= 10240;                               // Wk plain cast (2048 elems/block)
    size_t i = ((size_t)id * 256 + threadIdx.x) * 8;
    float4 x0 = *(const float4*)(Wk + i);
    float4 x1 = *(const float4*)(Wk + i + 4);
    uint4 u;
    u.x = pack2bf(x0.x,x0.y); u.y = pack2bf(x0.z,x0.w);
    u.z = pack2bf(x1.x,x1.y); u.w = pack2bf(x1.z,x1.w);
    *(uint4*)(WkB + i) = u;
  }
}

// ---------------- shared GEMM core: C[M,N](+=slice) = scale*A x Bt^T ----------------
// 128x128 tile, BK=64, 256 thr (4 waves 2x2), mfma_f32_16x16x32_bf16.
// mirror!=0: also write transposed tile (cooperative LDS epilogue, full lines).
__device__ __forceinline__ void gemm_core(
    const unsigned short* __restrict__ A, const unsigned short* __restrict__ Bt,
    float* __restrict__ Cf, unsigned short* __restrict__ Cb,
    int M, int N, int K, float scale, int mBase, int nBase,
    int kStart, int kChunk, int outBf16, int mirror, char* smem){
  unsigned short* sA = (unsigned short*)smem;
  unsigned short* sB = sA + 128 * 64;
  int tid = threadIdx.x, lane = tid & 63, wid = tid >> 6;
  int chRow = lane >> 3;
  int chCol = (lane & 7) * 8;
  int wm = wid >> 1, wn = wid & 1;

  f32x4 acc[4][4];
  #pragma unroll
  for(int i=0;i<4;i++)
    #pragma unroll
    for(int j=0;j<4;j++) acc[i][j] = (f32x4){0.f,0.f,0.f,0.f};

  for(int k0 = kStart; k0 < kStart + kChunk; k0 += 64){
    #pragma unroll
    for(int i = 0; i < 4; i++){
      int ch = wid * 4 + i;
      int arow = ch * 8 + chRow;
      gload16(A  + (size_t)(mBase + arow) * K + k0 + chCol, &sA[ch * 512]);
      gload16(Bt + (size_t)(nBase + arow) * K + k0 + chCol, &sB[ch * 512]);
    }
    __syncthreads();
    #pragma unroll
    for(int kk = 0; kk < 64; kk += 32){
      short8 a[4], b[4];
      int krd = kk + (lane >> 4) * 8;
      #pragma unroll
      for(int i = 0; i < 4; i++){
        int row = wm * 64 + i * 16 + (lane & 15);
        a[i] = *reinterpret_cast<const short8*>(&sA[row * 64 + krd]);
        int col = wn * 64 + i * 16 + (lane & 15);
        b[i] = *reinterpret_cast<const short8*>(&sB[col * 64 + krd]);
      }
      #pragma unroll
      for(int i = 0; i < 4; i++)
        #pragma unroll
        for(int j = 0; j < 4; j++)
          acc[i][j] = __builtin_amdgcn_mfma_f32_16x16x32_bf16(a[i], b[j], acc[i][j], 0, 0, 0);
    }
    __syncthreads();
  }

  #pragma unroll
  for(int i = 0; i < 4; i++){
    #pragma unroll
    for(int j = 0; j < 4; j++){
      int row = mBase + wm * 64 + i * 16 + (lane >> 4) * 4;
      int col = nBase + wn * 64 + j * 16 + (lane & 15);
      #pragma unroll
      for(int r = 0; r < 4; r++){
        float v = acc[i][j][r] * scale;
        size_t off = (size_t)(row + r) * N + col;
        if(outBf16) Cb[off] = f2bf(v);
        else        Cf[off] = v;
      }
    }
  }

  if(mirror && mBase != nBase){
    float* tf = (float*)smem;                 // 64 x 65 f32
    #pragma unroll
    for(int rq = 0; rq < 4; rq++){
      int qm = rq >> 1, qn = rq & 1;
      __syncthreads();
      if(wm == qm && wn == qn){
        #pragma unroll
        for(int i = 0; i < 4; i++)
          #pragma unroll
          for(int j = 0; j < 4; j++){
            int rl = i * 16 + (lane >> 4) * 4;
            int cl = j * 16 + (lane & 15);
            #pragma unroll
            for(int r = 0; r < 4; r++)
              tf[(rl + r) * 65 + cl] = acc[i][j][r] * scale;
          }
      }
      __syncthreads();
      int mr = tid >> 2, seg = tid & 3;
      size_t obase = (size_t)(nBase + qn * 64 + mr) * N + mBase + qm * 64 + seg * 16;
      #pragma unroll
      for(int k4 = 0; k4 < 4; k4++){
        float4 v;
        v.x = tf[(seg * 16 + k4 * 4 + 0) * 65 + mr];
        v.y = tf[(seg * 16 + k4 * 4 + 1) * 65 + mr];
        v.z = tf[(seg * 16 + k4 * 4 + 2) * 65 + mr];
        v.w = tf[(seg * 16 + k4 * 4 + 3) * 65 + mr];
        *(float4*)(Cf + obase + k4 * 4) = v;
      }
    }
  }
}

// ---- plain NT GEMM wrapper (2D grid + optional split-K z) ----
template<int OUT_BF16>
__global__ __launch_bounds__(256, 2)
void gemm_bt_kernel(const unsigned short* __restrict__ A,
                    const unsigned short* __restrict__ Bt,
                    float* __restrict__ Cf, unsigned short* __restrict__ Cb,
                    int M, int N, int K, float scale){
  __shared__ __align__(16) char smem[32768];
  int gx = gridDim.x, gy = gridDim.y;
  int nwg = gx * gy;
  int id = blockIdx.y * gx + blockIdx.x;
  if((nwg & 7) == 0){ int cpx = nwg >> 3; id = (id & 7) * cpx + (id >> 3); }
  int mBase = (id / gx) * 128, nBase = (id % gx) * 128;
  int kChunk = K / (int)gridDim.z;
  int kStart = kChunk * (int)blockIdx.z;
  if(!OUT_BF16) Cf += (size_t)blockIdx.z * M * N;
  gemm_core(A, Bt, Cf, Cb, M, N, K, scale, mBase, nBase, kStart, kChunk, OUT_BF16, 0, smem);
}

// ---- mega1: low_cos triangle [0,2080) | hc split-K [2080,2208) | k [2208,2336) ----
__global__ __launch_bounds__(256, 2)
void mega1_kernel(const unsigned short* __restrict__ lowN, float* __restrict__ out_lowcos,
                  const unsigned short* __restrict__ highN, float* __restrict__ hcPart,
                  const unsigned short* __restrict__ WkB, unsigned short* __restrict__ kB){
  __shared__ __align__(16) char smem[32768];
  int bid = blockIdx.x;
  if(bid < 2080){
    int id = (bid & 7) * 260 + (bid >> 3);     // XCD-chunked over 2080
    int Si = 0, rem = id;
    for(;;){ int rl = 10 + 16*(15 - Si); if(rem < rl) break; rem -= rl; Si++; }
    int bi, bj;
    if(rem < 10){
      int ti = 0;
      while((ti+1)*4 - (((ti+1)*ti) >> 1) <= rem) ti++;
      int off = ti*4 - ((ti*(ti-1)) >> 1);
      int tj = ti + (rem - off);
      bi = Si*4 + ti; bj = Si*4 + tj;
    } else {
      int r2 = rem - 10;
      int Sj = Si + 1 + (r2 >> 4);
      int t = r2 & 15;
      bi = Si*4 + (t >> 2); bj = Sj*4 + (t & 3);
    }
    gemm_core(lowN, lowN, out_lowcos, nullptr, NL, NL, DIMV, 1.0f,
              bi*128, bj*128, 0, DIMV, 0, 1, smem);
  } else if(bid < 2208){
    int id2 = bid - 2080;                      // 128 blocks: 8x8 x z2
    int z = id2 >> 6, w = id2 & 63;
    int s = (w & 7) * 8 + (w >> 3);
    gemm_core(highN, highN, hcPart + (size_t)z * 1048576, nullptr, NHI, NHI, DIMV, 1.0f,
              (s >> 3)*128, (s & 7)*128, z*1024, 1024, 0, 0, smem);
  } else {
    int id3 = bid - 2208;                      // 128 blocks: k = highN Wk^T, 8(M) x 16(N)
    int s = (id3 & 7) * 16 + (id3 >> 3);
    gemm_core(highN, WkB, nullptr, kB, NHI, DIMV, DIMV, 1.0f,
              (s >> 4)*128, (s & 15)*128, 0, DIMV, 1, 0, smem);
  }
}

// ---- megaAgg: agg split-K x2 [0,256) + colsum final [256,260) ----
__global__ __launch_bounds__(256, 2)
void megaagg_kernel(const unsigned short* __restrict__ lowNT,
                    const unsigned short* __restrict__ attnT, float* __restrict__ aggP,
                    const float* __restrict__ part, float* __restrict__ colsum){
  __shared__ __align__(16) char smem[32768];
  int bid = blockIdx.x;
  if(bid < 256){
    int z = bid >> 7, w = bid & 127;           // 128 blocks per z: 8(N) x 16(M)
    int s = (w & 7) * 16 + (w >> 3);
    gemm_core(lowNT, attnT, aggP + (size_t)z * 2097152, nullptr, DIMV, NHI, NL, 1.0f,
              (s >> 3)*128, (s & 7)*128, z*4096, 4096, 0, 0, smem);
  } else {
    int c = (bid - 256) * 256 + threadIdx.x;
    float s = 0.f;
    for(int i = 0; i < 256; i++) s += part[(size_t)i * NHI + c];
    colsum[c] = s;
  }
}

// ---- sparsemax (blocks [0,2048)) + high_cos combine (blocks [2048,2560)) ----
__global__ __launch_bounds__(256)
void sparsemax_kernel(float* __restrict__ S, unsigned short* __restrict__ attnBf,
                      const float* __restrict__ hcPart, float* __restrict__ out_highcos){
  int bid = blockIdx.x;
  if(bid >= 2048){
    size_t i = ((size_t)(bid - 2048) * 256 + threadIdx.x) * 8;
    float4 a0 = *(const float4*)(hcPart + i);
    float4 a1 = *(const float4*)(hcPart + i + 4);
    float4 b0 = *(const float4*)(hcPart + 1048576 + i);
    float4 b1 = *(const float4*)(hcPart + 1048576 + i + 4);
    *(float4*)(out_highcos + i)     = make_float4(a0.x+b0.x, a0.y+b0.y, a0.z+b0.z, a0.w+b0.w);
    *(float4*)(out_highcos + i + 4) = make_float4(a1.x+b1.x, a1.y+b1.y, a1.z+b1.z, a1.w+b1.w);
    return;
  }
  int wid = threadIdx.x >> 6, lane = threadIdx.x & 63;
  int row = bid * 4 + wid;
  float* z = S + (size_t)row * NHI;
  float v[16];
  #pragma unroll
  for(int j = 0; j < 16; j++) v[j] = z[j * 64 + lane];
  float mx = v[0];
  #pragma unroll
  for(int j = 1; j < 16; j++) mx = fmaxf(mx, v[j]);
  #pragma unroll
  for(int s = 1; s < 64; s <<= 1) mx = fmaxf(mx, __shfl_xor(mx, s, 64));
  float lo = mx - 1.0f, hi = mx;
  for(int it = 0; it < 40; it++){
    float mid = 0.5f * (lo + hi);
    float sum = 0.f;
    #pragma unroll
    for(int j = 0; j < 16; j++) sum += fmaxf(v[j] - mid, 0.f);
    #pragma unroll
    for(int s = 1; s < 64; s <<= 1) sum += __shfl_xor(sum, s, 64);
    if(sum >= 1.0f) lo = mid; else hi = mid;
  }
  float cnt = 0.f, ssum = 0.f;
  #pragma unroll
  for(int j = 0; j < 16; j++){
    if(v[j] > lo){ cnt += 1.f; ssum += v[j]; }
  }
  #pragma unroll
  for(int s = 1; s < 64; s <<= 1){
    cnt  += __shfl_xor(cnt,  s, 64);
    ssum += __shfl_xor(ssum, s, 64);
  }
  float tau = (ssum - 1.0f) / cnt;
  #pragma unroll
  for(int j = 0; j < 16; j++){
    float a = fmaxf(v[j] - tau, 0.f);
    z[j * 64 + lane] = a;
    attnBf[(size_t)row * NHI + j * 64 + lane] = f2bf(a);
  }
}

// ---- transposes [0,6656) + colsum_part [6656,6912) ----
__global__ __launch_bounds__(256)
void transpose3_kernel(const unsigned short* __restrict__ attnB, unsigned short* __restrict__ attnT,
                       const unsigned short* __restrict__ lowN,  unsigned short* __restrict__ lowNT,
                       const unsigned short* __restrict__ highN, unsigned short* __restrict__ highNT,
                       const float* __restrict__ attnF, float* __restrict__ part){
  int id = blockIdx.x;
  if(id >= 6656){
    int chunk = id - 6656;                    // 256 chunks x 32 rows
    int t = threadIdx.x;
    const float* p = attnF + (size_t)chunk * 32 * NHI;
    float a0=0,a1=0,a2=0,a3=0;
    for(int r = 0; r < 32; r++){
      a0 += p[(size_t)r*NHI + t];
      a1 += p[(size_t)r*NHI + t + 256];
      a2 += p[(size_t)r*NHI + t + 512];
      a3 += p[(size_t)r*NHI + t + 768];
    }
    float* q = part + (size_t)chunk * NHI;
    q[t]=a0; q[t+256]=a1; q[t+512]=a2; q[t+768]=a3;
    return;
  }
  __shared__ unsigned short tile[64][65];
  const unsigned short* in; unsigned short* out; int R, C, tx, ty;
  if(id < 2048){        in = attnB; out = attnT;  R = NL;  C = NHI;  tx = id & 15; ty = id >> 4; }
  else if(id < 6144){ id -= 2048;
                        in = lowN;  out = lowNT;  R = NL;  C = DIMV; tx = id & 31; ty = id >> 5; }
  else {              id -= 6144;
                        in = highN; out = highNT; R = NHI; C = DIMV; tx = id & 31; ty = id >> 5; }
  int c0 = tx * 64, r0 = ty * 64;
  int t = threadIdx.x;
  int ci = t & 63, r4 = t >> 6;
  #pragma unroll
  for(int k = 0; k < 16; k++){
    int r = k * 4 + r4;
    tile[r][ci] = in[(size_t)(r0 + r) * C + c0 + ci];
  }
  __syncthreads();
  #pragma unroll
  for(int k = 0; k < 16; k++){
    int cc = k * 4 + r4;
    out[(size_t)(c0 + cc) * R + r0 + ci] = tile[ci][cc];
  }
}

// ------ Mt[d,h] = highNT[d,h] + (sum_z aggP_z[d,h]) / (colsum[h]+eps) ------
__global__ __launch_bounds__(256)
void mt_kernel(const unsigned short* __restrict__ highNT, const float* __restrict__ aggP,
               const float* __restrict__ colsum, unsigned short* __restrict__ Mt){
  int idx = blockIdx.x * 256 + threadIdx.x;      // 2048*1024
  int h = idx & 1023;
  float s = aggP[idx] + aggP[idx + 2097152];
  float val = bf2f(highNT[idx]) + s / (colsum[h] + 1e-10f);
  Mt[idx] = f2bf(val);
}

extern "C" void kernel_launch(void* const* d_in, const int* in_sizes, int n_in,
                              void* d_out, int out_size, void* d_ws, size_t ws_size,
                              hipStream_t stream){
  const float* low_w  = (const float*)d_in[0];
  const float* high_w = (const float*)d_in[1];
  const float* Wq     = (const float*)d_in[2];
  const float* Wk     = (const float*)d_in[3];
  float* out = (float*)d_out;

  char* ws = (char*)d_ws;
  unsigned short* lowN  = (unsigned short*)(ws);                 // 32 MB; dead after transpose3
  float*          aggP  = (float*)(ws);                          // reuses lowN: 2x8MB partials
  unsigned short* highN = (unsigned short*)(ws + 33554432);      //  4 MB
  unsigned short* WqT   = (unsigned short*)(ws + 37748736);      //  8 MB; dead after R2t
  unsigned short* WkB   = (unsigned short*)(ws + 46137344);      //  8 MB; dead after k
  unsigned short* attnB = (unsigned short*)(ws + 37748736);      // reuse WqT/WkB (16 MB)
  unsigned short* kB    = (unsigned short*)(ws + 54525952);      //  4 MB; dead after R2t
  unsigned short* R2t   = (unsigned short*)(ws + 62914560);      //  4 MB; dead after scores
  unsigned short* lowNT = (unsigned short*)(ws + 54525952);      // 32 MB (from transpose3)
  float*          part  = (float*)(ws + 88080384);               //  1 MB
  float*          colsum= (float*)(ws + 88080384 + 1048576);     //  4 KB
  unsigned short* attnT = (unsigned short*)(ws + 92274688);      // 16 MB (from transpose3)
  float*          hcPart= (float*)(ws + 109051904);              //  8 MB; dead after sparsemax
  unsigned short* Mt    = (unsigned short*)(ws + 109051904);     //  4 MB (written at step 8)
  unsigned short* highNT= (unsigned short*)(ws + 113246208);     //  4 MB (from transpose3)

  float* out_lowc    = out;               // [8192,2048]
  float* out_lowcos  = out + 16777216;    // [8192,8192]
  float* out_high    = out + 83886080;    // [8192,2048]
  float* out_highcos = out + 100663296;   // [1024,1024]
  float* out_attn    = out + 101711872;   // [8192,1024]

  const float scl = 1.0f / sqrtf((float)DIMV);

  // 1. fused prep: normalize rows + castT(Wq) + cast(Wk)
  prep_kernel<<<12288, 256, 0, stream>>>(low_w, high_w, Wq, Wk,
                                         out_lowc, lowN, highN, WqT, WkB);
  // 2. mega1: low_cos triangle+mirror | high_cos split-K | k = highN Wk^T
  mega1_kernel<<<2336, 256, 0, stream>>>(lowN, out_lowcos, highN, hcPart, WkB, kB);
  // 3. R2t[h,d] = sum_o k[h,o] Wq[o,d]  (NT with WqT)
  gemm_bt_kernel<1><<<dim3(16,8), 256, 0, stream>>>(kB, WqT, nullptr, R2t,
                                                    NHI, DIMV, DIMV, 1.0f);
  // 4. scores = scl * lowN R2t^T -> f32 into attn slot
  gemm_bt_kernel<0><<<dim3(8,64), 256, 0, stream>>>(lowN, R2t, out_attn, nullptr,
                                                    NL, NHI, DIMV, scl);
  // 5. sparsemax rows (+ bf16 copy) + fused high_cos combine
  sparsemax_kernel<<<2560, 256, 0, stream>>>(out_attn, attnB, hcPart, out_highcos);
  // 6. transposes (attnT, lowNT, highNT) + colsum partials
  transpose3_kernel<<<6912, 256, 0, stream>>>(attnB, attnT, lowN, lowNT, highN, highNT,
                                              out_attn, part);
  // 7. megaAgg: agg split-K x2 + colsum final
  megaagg_kernel<<<260, 256, 0, stream>>>(lowNT, attnT, aggP, part, colsum);
  // 8. Mt = highN^T + agg / colsum
  mt_kernel<<<8192, 256, 0, stream>>>(highNT, aggP, colsum, Mt);
  // 9. output_high = attn Mt^T
  gemm_bt_kernel<0><<<dim3(16,64), 256, 0, stream>>>(attnB, Mt, out_high, nullptr,
                                                     NL, DIMV, NHI, 1.0f);
}

// Round 14
// 546.294 us; speedup vs baseline: 1.0015x; 1.0015x over previous
//
#include <hip/hip_runtime.h>
#include <hip/hip_bf16.h>
#include <stdint.h>

#define NL   8192
#define NHI  1024
#define DIMV 2048

typedef __attribute__((ext_vector_type(8))) short short8;
typedef __attribute__((ext_vector_type(4))) float f32x4;

__device__ __forceinline__ unsigned short f2bf(float x){
  unsigned u = __float_as_uint(x);
  u += 0x7FFFu + ((u >> 16) & 1u);
  return (unsigned short)(u >> 16);
}
__device__ __forceinline__ float bf2f(unsigned short b){
  return __uint_as_float(((unsigned)b) << 16);
}
__device__ __forceinline__ unsigned pack2bf(float a, float b){
  return (unsigned)f2bf(a) | ((unsigned)f2bf(b) << 16);
}

__device__ __forceinline__ void gload16(const void* g, void* l){
  __builtin_amdgcn_global_load_lds(
      (const __attribute__((address_space(1))) unsigned int*)g,
      (__attribute__((address_space(3))) unsigned int*)l, 16, 0, 0);
}

// ---- fused prep: rownorm(low)+rownorm(high) [0,9216) | castT(Wq) [9216,10240)
//      | plain cast(Wk) [10240,12288) ----
__global__ __launch_bounds__(256)
void prep_kernel(const float* __restrict__ low_w, const float* __restrict__ high_w,
                 const float* __restrict__ Wq, const float* __restrict__ Wk,
                 float* __restrict__ out_lowc, unsigned short* __restrict__ lowN,
                 unsigned short* __restrict__ highN,
                 unsigned short* __restrict__ WqT, unsigned short* __restrict__ WkB){
  __shared__ __align__(16) char smem[8448];
  int id = blockIdx.x;
  if(id < 9216){
    const float* W; float* oF; unsigned short* oB; int row;
    if(id < 8192){ W = low_w; oF = out_lowc; oB = lowN; row = id; }
    else         { W = high_w; oF = nullptr; oB = highN; row = id - 8192; }
    const float* r = W + (size_t)row * DIMV;
    int base = threadIdx.x * 8;
    float4 x0 = *(const float4*)(r + base);
    float4 x1 = *(const float4*)(r + base + 4);
    float ss = x0.x*x0.x + x0.y*x0.y + x0.z*x0.z + x0.w*x0.w
             + x1.x*x1.x + x1.y*x1.y + x1.z*x1.z + x1.w*x1.w;
    #pragma unroll
    for(int s = 1; s < 64; s <<= 1) ss += __shfl_xor(ss, s, 64);
    float* red = (float*)smem;
    if((threadIdx.x & 63) == 0) red[threadIdx.x >> 6] = ss;
    __syncthreads();
    float tot = red[0] + red[1] + red[2] + red[3];
    float inv = 1.0f / sqrtf(tot);
    float y0=x0.x*inv, y1=x0.y*inv, y2=x0.z*inv, y3=x0.w*inv;
    float y4=x1.x*inv, y5=x1.y*inv, y6=x1.z*inv, y7=x1.w*inv;
    if(oF){
      float* o = oF + (size_t)row * DIMV + base;
      *(float4*)o       = make_float4(y0,y1,y2,y3);
      *(float4*)(o + 4) = make_float4(y4,y5,y6,y7);
    }
    uint4 u;
    u.x = pack2bf(y0,y1); u.y = pack2bf(y2,y3);
    u.z = pack2bf(y4,y5); u.w = pack2bf(y6,y7);
    *(uint4*)(oB + (size_t)row * DIMV + base) = u;
  } else if(id < 10240){
    id -= 9216;                                // Wq cast+transpose tiles
    unsigned short (*tile)[65] = (unsigned short(*)[65])smem;
    int tx = id & 31, ty = id >> 5;
    int c0 = tx * 64, r0 = ty * 64;
    int t = threadIdx.x;
    int ci = t & 63, r4 = t >> 6;
    #pragma unroll
    for(int k = 0; k < 16; k++){
      int r = k * 4 + r4;
      tile[r][ci] = f2bf(Wq[(size_t)(r0 + r) * 2048 + c0 + ci]);
    }
    __syncthreads();
    #pragma unroll
    for(int k = 0; k < 16; k++){
      int cc = k * 4 + r4;
      WqT[(size_t)(c0 + cc) * 2048 + r0 + ci] = tile[ci][cc];
    }
  } else {
    id -= 10240;                               // Wk plain cast (2048 elems/block)
    size_t i = ((size_t)id * 256 + threadIdx.x) * 8;
    float4 x0 = *(const float4*)(Wk + i);
    float4 x1 = *(const float4*)(Wk + i + 4);
    uint4 u;
    u.x = pack2bf(x0.x,x0.y); u.y = pack2bf(x0.z,x0.w);
    u.z = pack2bf(x1.x,x1.y); u.w = pack2bf(x1.z,x1.w);
    *(uint4*)(WkB + i) = u;
  }
}

// ---------------- shared GEMM core: C[M,N](+=slice) = scale*A x Bt^T ----------------
// 128x128 tile, BK=64, 256 thr (4 waves 2x2), mfma_f32_16x16x32_bf16.
// mirror!=0: also write transposed tile via ping-pong LDS epilogue:
//   pre-fill tf0; slot rq = { owner(rq+1) fills other buf || all write tf(rq) } + 1 barrier.
//   4 barriers total (was 8); fill overlaps global writes. Needs 33280 B smem.
__device__ __forceinline__ void gemm_core(
    const unsigned short* __restrict__ A, const unsigned short* __restrict__ Bt,
    float* __restrict__ Cf, unsigned short* __restrict__ Cb,
    int M, int N, int K, float scale, int mBase, int nBase,
    int kStart, int kChunk, int outBf16, int mirror, char* smem){
  unsigned short* sA = (unsigned short*)smem;
  unsigned short* sB = sA + 128 * 64;
  int tid = threadIdx.x, lane = tid & 63, wid = tid >> 6;
  int chRow = lane >> 3;
  int chCol = (lane & 7) * 8;
  int wm = wid >> 1, wn = wid & 1;

  f32x4 acc[4][4];
  #pragma unroll
  for(int i=0;i<4;i++)
    #pragma unroll
    for(int j=0;j<4;j++) acc[i][j] = (f32x4){0.f,0.f,0.f,0.f};

  for(int k0 = kStart; k0 < kStart + kChunk; k0 += 64){
    #pragma unroll
    for(int i = 0; i < 4; i++){
      int ch = wid * 4 + i;
      int arow = ch * 8 + chRow;
      gload16(A  + (size_t)(mBase + arow) * K + k0 + chCol, &sA[ch * 512]);
      gload16(Bt + (size_t)(nBase + arow) * K + k0 + chCol, &sB[ch * 512]);
    }
    __syncthreads();
    #pragma unroll
    for(int kk = 0; kk < 64; kk += 32){
      short8 a[4], b[4];
      int krd = kk + (lane >> 4) * 8;
      #pragma unroll
      for(int i = 0; i < 4; i++){
        int row = wm * 64 + i * 16 + (lane & 15);
        a[i] = *reinterpret_cast<const short8*>(&sA[row * 64 + krd]);
        int col = wn * 64 + i * 16 + (lane & 15);
        b[i] = *reinterpret_cast<const short8*>(&sB[col * 64 + krd]);
      }
      #pragma unroll
      for(int i = 0; i < 4; i++)
        #pragma unroll
        for(int j = 0; j < 4; j++)
          acc[i][j] = __builtin_amdgcn_mfma_f32_16x16x32_bf16(a[i], b[j], acc[i][j], 0, 0, 0);
    }
    __syncthreads();
  }

  #pragma unroll
  for(int i = 0; i < 4; i++){
    #pragma unroll
    for(int j = 0; j < 4; j++){
      int row = mBase + wm * 64 + i * 16 + (lane >> 4) * 4;
      int col = nBase + wn * 64 + j * 16 + (lane & 15);
      #pragma unroll
      for(int r = 0; r < 4; r++){
        float v = acc[i][j][r] * scale;
        size_t off = (size_t)(row + r) * N + col;
        if(outBf16) Cb[off] = f2bf(v);
        else        Cf[off] = v;
      }
    }
  }

  if(mirror && mBase != nBase){
    // ping-pong transposed-tile epilogue (sA/sB dead: compute loop ended with barrier)
    float* bufs[2] = { (float*)smem, (float*)(smem + 16640) };   // 64x65 f32 each
    int ln15 = lane & 15, lh = lane >> 4;
    // pre-fill round 0 (owner wave wm==0,wn==0)
    if(wm == 0 && wn == 0){
      float* tf = bufs[0];
      #pragma unroll
      for(int i = 0; i < 4; i++)
        #pragma unroll
        for(int j = 0; j < 4; j++){
          int rl = i * 16 + lh * 4;
          int cl = j * 16 + ln15;
          #pragma unroll
          for(int r = 0; r < 4; r++)
            tf[(rl + r) * 65 + cl] = acc[i][j][r] * scale;
        }
    }
    __syncthreads();
    #pragma unroll
    for(int rq = 0; rq < 4; rq++){
      // owner of round rq+1 fills the other buffer (overlaps global writes below)
      if(rq < 3){
        int nq = rq + 1, qm = nq >> 1, qn = nq & 1;
        if(wm == qm && wn == qn){
          float* tf = bufs[(rq + 1) & 1];
          #pragma unroll
          for(int i = 0; i < 4; i++)
            #pragma unroll
            for(int j = 0; j < 4; j++){
              int rl = i * 16 + lh * 4;
              int cl = j * 16 + ln15;
              #pragma unroll
              for(int r = 0; r < 4; r++)
                tf[(rl + r) * 65 + cl] = acc[i][j][r] * scale;
            }
        }
      }
      // cooperative coalesced write of round rq's transposed 64x64 quadrant
      {
        float* tf = bufs[rq & 1];
        int qm = rq >> 1, qn = rq & 1;
        int mr = tid >> 2, seg = tid & 3;
        size_t obase = (size_t)(nBase + qn * 64 + mr) * N + mBase + qm * 64 + seg * 16;
        #pragma unroll
        for(int k4 = 0; k4 < 4; k4++){
          float4 v;
          v.x = tf[(seg * 16 + k4 * 4 + 0) * 65 + mr];
          v.y = tf[(seg * 16 + k4 * 4 + 1) * 65 + mr];
          v.z = tf[(seg * 16 + k4 * 4 + 2) * 65 + mr];
          v.w = tf[(seg * 16 + k4 * 4 + 3) * 65 + mr];
          *(float4*)(Cf + obase + k4 * 4) = v;
        }
      }
      __syncthreads();
    }
  }
}

// ---- plain NT GEMM wrapper (2D grid + optional split-K z) ----
template<int OUT_BF16>
__global__ __launch_bounds__(256, 2)
void gemm_bt_kernel(const unsigned short* __restrict__ A,
                    const unsigned short* __restrict__ Bt,
                    float* __restrict__ Cf, unsigned short* __restrict__ Cb,
                    int M, int N, int K, float scale){
  __shared__ __align__(16) char smem[32768];
  int gx = gridDim.x, gy = gridDim.y;
  int nwg = gx * gy;
  int id = blockIdx.y * gx + blockIdx.x;
  if((nwg & 7) == 0){ int cpx = nwg >> 3; id = (id & 7) * cpx + (id >> 3); }
  int mBase = (id / gx) * 128, nBase = (id % gx) * 128;
  int kChunk = K / (int)gridDim.z;
  int kStart = kChunk * (int)blockIdx.z;
  if(!OUT_BF16) Cf += (size_t)blockIdx.z * M * N;
  gemm_core(A, Bt, Cf, Cb, M, N, K, scale, mBase, nBase, kStart, kChunk, OUT_BF16, 0, smem);
}

// ---- mega1: low_cos triangle [0,2080) | hc split-K [2080,2208) | k [2208,2336) ----
__global__ __launch_bounds__(256, 2)
void mega1_kernel(const unsigned short* __restrict__ lowN, float* __restrict__ out_lowcos,
                  const unsigned short* __restrict__ highN, float* __restrict__ hcPart,
                  const unsigned short* __restrict__ WkB, unsigned short* __restrict__ kB){
  __shared__ __align__(16) char smem[33280];   // 32768 staging | 2x16640 mirror ping-pong
  int bid = blockIdx.x;
  if(bid < 2080){
    int id = (bid & 7) * 260 + (bid >> 3);     // XCD-chunked over 2080
    int Si = 0, rem = id;
    for(;;){ int rl = 10 + 16*(15 - Si); if(rem < rl) break; rem -= rl; Si++; }
    int bi, bj;
    if(rem < 10){
      int ti = 0;
      while((ti+1)*4 - (((ti+1)*ti) >> 1) <= rem) ti++;
      int off = ti*4 - ((ti*(ti-1)) >> 1);
      int tj = ti + (rem - off);
      bi = Si*4 + ti; bj = Si*4 + tj;
    } else {
      int r2 = rem - 10;
      int Sj = Si + 1 + (r2 >> 4);
      int t = r2 & 15;
      bi = Si*4 + (t >> 2); bj = Sj*4 + (t & 3);
    }
    gemm_core(lowN, lowN, out_lowcos, nullptr, NL, NL, DIMV, 1.0f,
              bi*128, bj*128, 0, DIMV, 0, 1, smem);
  } else if(bid < 2208){
    int id2 = bid - 2080;                      // 128 blocks: 8x8 x z2
    int z = id2 >> 6, w = id2 & 63;
    int s = (w & 7) * 8 + (w >> 3);
    gemm_core(highN, highN, hcPart + (size_t)z * 1048576, nullptr, NHI, NHI, DIMV, 1.0f,
              (s >> 3)*128, (s & 7)*128, z*1024, 1024, 0, 0, smem);
  } else {
    int id3 = bid - 2208;                      // 128 blocks: k = highN Wk^T, 8(M) x 16(N)
    int s = (id3 & 7) * 16 + (id3 >> 3);
    gemm_core(highN, WkB, nullptr, kB, NHI, DIMV, DIMV, 1.0f,
              (s >> 4)*128, (s & 15)*128, 0, DIMV, 1, 0, smem);
  }
}

// ---- megaAgg: agg split-K x2 [0,256) + colsum final [256,260) ----
__global__ __launch_bounds__(256, 2)
void megaagg_kernel(const unsigned short* __restrict__ lowNT,
                    const unsigned short* __restrict__ attnT, float* __restrict__ aggP,
                    const float* __restrict__ part, float* __restrict__ colsum){
  __shared__ __align__(16) char smem[32768];
  int bid = blockIdx.x;
  if(bid < 256){
    int z = bid >> 7, w = bid & 127;           // 128 blocks per z: 8(N) x 16(M)
    int s = (w & 7) * 16 + (w >> 3);
    gemm_core(lowNT, attnT, aggP + (size_t)z * 2097152, nullptr, DIMV, NHI, NL, 1.0f,
              (s >> 3)*128, (s & 7)*128, z*4096, 4096, 0, 0, smem);
  } else {
    int c = (bid - 256) * 256 + threadIdx.x;
    float s = 0.f;
    for(int i = 0; i < 256; i++) s += part[(size_t)i * NHI + c];
    colsum[c] = s;
  }
}

// ---- sparsemax (blocks [0,2048)) + high_cos combine (blocks [2048,2560)) ----
__global__ __launch_bounds__(256)
void sparsemax_kernel(float* __restrict__ S, unsigned short* __restrict__ attnBf,
                      const float* __restrict__ hcPart, float* __restrict__ out_highcos){
  int bid = blockIdx.x;
  if(bid >= 2048){
    size_t i = ((size_t)(bid - 2048) * 256 + threadIdx.x) * 8;
    float4 a0 = *(const float4*)(hcPart + i);
    float4 a1 = *(const float4*)(hcPart + i + 4);
    float4 b0 = *(const float4*)(hcPart + 1048576 + i);
    float4 b1 = *(const float4*)(hcPart + 1048576 + i + 4);
    *(float4*)(out_highcos + i)     = make_float4(a0.x+b0.x, a0.y+b0.y, a0.z+b0.z, a0.w+b0.w);
    *(float4*)(out_highcos + i + 4) = make_float4(a1.x+b1.x, a1.y+b1.y, a1.z+b1.z, a1.w+b1.w);
    return;
  }
  int wid = threadIdx.x >> 6, lane = threadIdx.x & 63;
  int row = bid * 4 + wid;
  float* z = S + (size_t)row * NHI;
  float v[16];
  #pragma unroll
  for(int j = 0; j < 16; j++) v[j] = z[j * 64 + lane];
  float mx = v[0];
  #pragma unroll
  for(int j = 1; j < 16; j++) mx = fmaxf(mx, v[j]);
  #pragma unroll
  for(int s = 1; s < 64; s <<= 1) mx = fmaxf(mx, __shfl_xor(mx, s, 64));
  float lo = mx - 1.0f, hi = mx;
  for(int it = 0; it < 40; it++){
    float mid = 0.5f * (lo + hi);
    float sum = 0.f;
    #pragma unroll
    for(int j = 0; j < 16; j++) sum += fmaxf(v[j] - mid, 0.f);
    #pragma unroll
    for(int s = 1; s < 64; s <<= 1) sum += __shfl_xor(sum, s, 64);
    if(sum >= 1.0f) lo = mid; else hi = mid;
  }
  float cnt = 0.f, ssum = 0.f;
  #pragma unroll
  for(int j = 0; j < 16; j++){
    if(v[j] > lo){ cnt += 1.f; ssum += v[j]; }
  }
  #pragma unroll
  for(int s = 1; s < 64; s <<= 1){
    cnt  += __shfl_xor(cnt,  s, 64);
    ssum += __shfl_xor(ssum, s, 64);
  }
  float tau = (ssum - 1.0f) / cnt;
  #pragma unroll
  for(int j = 0; j < 16; j++){
    float a = fmaxf(v[j] - tau, 0.f);
    z[j * 64 + lane] = a;
    attnBf[(size_t)row * NHI + j * 64 + lane] = f2bf(a);
  }
}

// ---- transposes [0,6656) + colsum_part [6656,6912) ----
__global__ __launch_bounds__(256)
void transpose3_kernel(const unsigned short* __restrict__ attnB, unsigned short* __restrict__ attnT,
                       const unsigned short* __restrict__ lowN,  unsigned short* __restrict__ lowNT,
                       const unsigned short* __restrict__ highN, unsigned short* __restrict__ highNT,
                       const float* __restrict__ attnF, float* __restrict__ part){
  int id = blockIdx.x;
  if(id >= 6656){
    int chunk = id - 6656;                    // 256 chunks x 32 rows
    int t = threadIdx.x;
    const float* p = attnF + (size_t)chunk * 32 * NHI;
    float a0=0,a1=0,a2=0,a3=0;
    for(int r = 0; r < 32; r++){
      a0 += p[(size_t)r*NHI + t];
      a1 += p[(size_t)r*NHI + t + 256];
      a2 += p[(size_t)r*NHI + t + 512];
      a3 += p[(size_t)r*NHI + t + 768];
    }
    float* q = part + (size_t)chunk * NHI;
    q[t]=a0; q[t+256]=a1; q[t+512]=a2; q[t+768]=a3;
    return;
  }
  __shared__ unsigned short tile[64][65];
  const unsigned short* in; unsigned short* out; int R, C, tx, ty;
  if(id < 2048){        in = attnB; out = attnT;  R = NL;  C = NHI;  tx = id & 15; ty = id >> 4; }
  else if(id < 6144){ id -= 2048;
                        in = lowN;  out = lowNT;  R = NL;  C = DIMV; tx = id & 31; ty = id >> 5; }
  else {              id -= 6144;
                        in = highN; out = highNT; R = NHI; C = DIMV; tx = id & 31; ty = id >> 5; }
  int c0 = tx * 64, r0 = ty * 64;
  int t = threadIdx.x;
  int ci = t & 63, r4 = t >> 6;
  #pragma unroll
  for(int k = 0; k < 16; k++){
    int r = k * 4 + r4;
    tile[r][ci] = in[(size_t)(r0 + r) * C + c0 + ci];
  }
  __syncthreads();
  #pragma unroll
  for(int k = 0; k < 16; k++){
    int cc = k * 4 + r4;
    out[(size_t)(c0 + cc) * R + r0 + ci] = tile[ci][cc];
  }
}

// ------ Mt[d,h] = highNT[d,h] + (sum_z aggP_z[d,h]) / (colsum[h]+eps) ------
__global__ __launch_bounds__(256)
void mt_kernel(const unsigned short* __restrict__ highNT, const float* __restrict__ aggP,
               const float* __restrict__ colsum, unsigned short* __restrict__ Mt){
  int idx = blockIdx.x * 256 + threadIdx.x;      // 2048*1024
  int h = idx & 1023;
  float s = aggP[idx] + aggP[idx + 2097152];
  float val = bf2f(highNT[idx]) + s / (colsum[h] + 1e-10f);
  Mt[idx] = f2bf(val);
}

extern "C" void kernel_launch(void* const* d_in, const int* in_sizes, int n_in,
                              void* d_out, int out_size, void* d_ws, size_t ws_size,
                              hipStream_t stream){
  const float* low_w  = (const float*)d_in[0];
  const float* high_w = (const float*)d_in[1];
  const float* Wq     = (const float*)d_in[2];
  const float* Wk     = (const float*)d_in[3];
  float* out = (float*)d_out;

  char* ws = (char*)d_ws;
  unsigned short* lowN  = (unsigned short*)(ws);                 // 32 MB; dead after transpose3
  float*          aggP  = (float*)(ws);                          // reuses lowN: 2x8MB partials
  unsigned short* highN = (unsigned short*)(ws + 33554432);      //  4 MB
  unsigned short* WqT   = (unsigned short*)(ws + 37748736);      //  8 MB; dead after R2t
  unsigned short* WkB   = (unsigned short*)(ws + 46137344);      //  8 MB; dead after k
  unsigned short* attnB = (unsigned short*)(ws + 37748736);      // reuse WqT/WkB (16 MB)
  unsigned short* kB    = (unsigned short*)(ws + 54525952);      //  4 MB; dead after R2t
  unsigned short* R2t   = (unsigned short*)(ws + 62914560);      //  4 MB; dead after scores
  unsigned short* lowNT = (unsigned short*)(ws + 54525952);      // 32 MB (from transpose3)
  float*          part  = (float*)(ws + 88080384);               //  1 MB
  float*          colsum= (float*)(ws + 88080384 + 1048576);     //  4 KB
  unsigned short* attnT = (unsigned short*)(ws + 92274688);      // 16 MB (from transpose3)
  float*          hcPart= (float*)(ws + 109051904);              //  8 MB; dead after sparsemax
  unsigned short* Mt    = (unsigned short*)(ws + 109051904);     //  4 MB (written at step 8)
  unsigned short* highNT= (unsigned short*)(ws + 113246208);     //  4 MB (from transpose3)

  float* out_lowc    = out;               // [8192,2048]
  float* out_lowcos  = out + 16777216;    // [8192,8192]
  float* out_high    = out + 83886080;    // [8192,2048]
  float* out_highcos = out + 100663296;   // [1024,1024]
  float* out_attn    = out + 101711872;   // [8192,1024]

  const float scl = 1.0f / sqrtf((float)DIMV);

  // 1. fused prep: normalize rows + castT(Wq) + cast(Wk)
  prep_kernel<<<12288, 256, 0, stream>>>(low_w, high_w, Wq, Wk,
                                         out_lowc, lowN, highN, WqT, WkB);
  // 2. mega1: low_cos triangle+mirror | high_cos split-K | k = highN Wk^T
  mega1_kernel<<<2336, 256, 0, stream>>>(lowN, out_lowcos, highN, hcPart, WkB, kB);
  // 3. R2t[h,d] = sum_o k[h,o] Wq[o,d]  (NT with WqT)
  gemm_bt_kernel<1><<<dim3(16,8), 256, 0, stream>>>(kB, WqT, nullptr, R2t,
                                                    NHI, DIMV, DIMV, 1.0f);
  // 4. scores = scl * lowN R2t^T -> f32 into attn slot
  gemm_bt_kernel<0><<<dim3(8,64), 256, 0, stream>>>(lowN, R2t, out_attn, nullptr,
                                                    NL, NHI, DIMV, scl);
  // 5. sparsemax rows (+ bf16 copy) + fused high_cos combine
  sparsemax_kernel<<<2560, 256, 0, stream>>>(out_attn, attnB, hcPart, out_highcos);
  // 6. transposes (attnT, lowNT, highNT) + colsum partials
  transpose3_kernel<<<6912, 256, 0, stream>>>(attnB, attnT, lowN, lowNT, highN, highNT,
                                              out_attn, part);
  // 7. megaAgg: agg split-K x2 + colsum final
  megaagg_kernel<<<260, 256, 0, stream>>>(lowNT, attnT, aggP, part, colsum);
  // 8. Mt = highN^T + agg / colsum
  mt_kernel<<<8192, 256, 0, stream>>>(highNT, aggP, colsum, Mt);
  // 9. output_high = attn Mt^T
  gemm_bt_kernel<0><<<dim3(16,64), 256, 0, stream>>>(attnB, Mt, out_high, nullptr,
                                                     NL, DIMV, NHI, 1.0f);
}